// Round 1
// baseline (1444.291 us; speedup 1.0000x reference)
//
#include <hip/hip_runtime.h>
#include <cstddef>
#include <cstdint>

#define B_ 8
#define N_ 4096
#define C_ 512
#define H_ 8
#define HD_ 64
#define BH_ 64

__device__ __forceinline__ float softplusf(float p) {
  return (p > 20.f) ? p : log1pf(expf(p));
}

// ---------------- tiled fp32 GEMM ----------------
// C[m,n] = act( A[m,:] @ W[:,n] (+bias[n]) ),   columns < split -> out0 (relu_lo), else out1 (relu_hi)
// relu means: fmax(v,0)+1e-6
__global__ __launch_bounds__(256) void gemm_tiled(
    const float* __restrict__ A, const float* __restrict__ W,
    const float* __restrict__ bias,
    float* __restrict__ out0, float* __restrict__ out1,
    int M, int Nn, int K, int split, int relu_lo, int relu_hi)
{
  __shared__ float As[32][68];  // [k][m] transposed
  __shared__ float Bs[32][68];  // [k][n]
  const int bm = blockIdx.x, bn = blockIdx.y;
  const int tid = threadIdx.x;
  const int tx = tid & 15, ty = tid >> 4;
  const int row0 = bm * 64, col0 = bn * 64;
  float acc[4][4] = {};
  for (int k0 = 0; k0 < K; k0 += 32) {
    {
      const int r  = tid >> 3;        // 0..31
      const int c4 = (tid & 7) * 4;   // 0..28
      #pragma unroll
      for (int rr = 0; rr < 64; rr += 32) {
        const float4 v = *(const float4*)&A[(size_t)(row0 + r + rr) * K + k0 + c4];
        As[c4 + 0][r + rr] = v.x;
        As[c4 + 1][r + rr] = v.y;
        As[c4 + 2][r + rr] = v.z;
        As[c4 + 3][r + rr] = v.w;
      }
      const int kr = tid >> 4;        // 0..15
      const int cb = (tid & 15) * 4;  // 0..60
      #pragma unroll
      for (int kk = 0; kk < 32; kk += 16) {
        *(float4*)&Bs[kr + kk][cb] =
            *(const float4*)&W[(size_t)(k0 + kr + kk) * Nn + col0 + cb];
      }
    }
    __syncthreads();
    #pragma unroll
    for (int kk = 0; kk < 32; ++kk) {
      const float4 a = *(const float4*)&As[kk][ty * 4];
      const float4 b = *(const float4*)&Bs[kk][tx * 4];
      const float av[4] = {a.x, a.y, a.z, a.w};
      const float bv[4] = {b.x, b.y, b.z, b.w};
      #pragma unroll
      for (int i = 0; i < 4; ++i)
        #pragma unroll
        for (int j = 0; j < 4; ++j)
          acc[i][j] = fmaf(av[i], bv[j], acc[i][j]);
    }
    __syncthreads();
  }
  float* dest; int ldd, ccol0, relu;
  if (col0 < split) { dest = out0; ldd = split;      ccol0 = col0;         relu = relu_lo; }
  else              { dest = out1; ldd = Nn - split; ccol0 = col0 - split; relu = relu_hi; }
  #pragma unroll
  for (int i = 0; i < 4; ++i) {
    const int row = row0 + ty * 4 + i;
    float vv[4];
    #pragma unroll
    for (int j = 0; j < 4; ++j) {
      float v = acc[i][j];
      if (bias) v += bias[col0 + tx * 4 + j];
      if (relu) v = fmaxf(v, 0.f) + 1e-6f;
      vv[j] = v;
    }
    *(float4*)&dest[(size_t)row * ldd + ccol0 + tx * 4] =
        make_float4(vv[0], vv[1], vv[2], vv[3]);
  }
}

// ---------------- focus: t /= softplus(sp); t = t^3 * ||t|| / ||t^3||  (row-wise, C=512) ----------------
__global__ __launch_bounds__(64) void focus_kernel(float* __restrict__ t, const float* __restrict__ sp)
{
  const int row = blockIdx.x;
  const int lane = threadIdx.x;
  float* p = t + (size_t)row * C_ + lane * 8;
  const float4 a = *(const float4*)p;
  const float4 b = *(const float4*)(p + 4);
  float tv[8] = {a.x, a.y, a.z, a.w, b.x, b.y, b.z, b.w};
  float s2 = 0.f, s6 = 0.f;
  #pragma unroll
  for (int i = 0; i < 8; ++i) {
    const float sc = softplusf(sp[lane * 8 + i]);
    const float x = tv[i] / sc;
    tv[i] = x;
    const float x3 = x * x * x;
    s2 = fmaf(x, x, s2);
    s6 = fmaf(x3, x3, s6);
  }
  #pragma unroll
  for (int off = 32; off > 0; off >>= 1) {
    s2 += __shfl_xor(s2, off);
    s6 += __shfl_xor(s6, off);
  }
  const float f = sqrtf(s2 / s6);
  float o[8];
  #pragma unroll
  for (int i = 0; i < 8; ++i) o[i] = tv[i] * tv[i] * tv[i] * f;
  *(float4*)p       = make_float4(o[0], o[1], o[2], o[3]);
  *(float4*)(p + 4) = make_float4(o[4], o[5], o[6], o[7]);
}

// ---------------- ksum[bh][c] = sum_n k[bh][n][c]  (atomic split over N) ----------------
__global__ __launch_bounds__(256) void ksum_kernel(const float* __restrict__ kf, float* __restrict__ ksum)
{
  const int bh = blockIdx.x, b = bh >> 3, h = bh & 7;
  const int c  = threadIdx.x & 63;
  const int rq = threadIdx.x >> 6;  // 0..3
  const int n0 = blockIdx.y * 256;
  float s = 0.f;
  for (int r = rq; r < 256; r += 4)
    s += kf[((size_t)(b * N_ + n0 + r)) * C_ + h * 64 + c];
  atomicAdd(&ksum[bh * 64 + c], s);
}

// ---------------- kvm[bh][c][d] = sum_n k[bh][n][c] * v[bh][n][d]  (split-K over N, atomic) ----------------
__global__ __launch_bounds__(256) void kvm_kernel(
    const float* __restrict__ kf, const float* __restrict__ vf, float* __restrict__ kvm)
{
  __shared__ float Ks[32][68];
  __shared__ float Vs[32][68];
  const int bh = blockIdx.x, b = bh >> 3, h = bh & 7;
  const int n0 = blockIdx.y * 512;
  const int tid = threadIdx.x;
  const int tx = tid & 15, ty = tid >> 4;
  float acc[4][4] = {};
  for (int nb = 0; nb < 512; nb += 32) {
    const int r  = tid >> 3;        // 0..31
    const int cg = (tid & 7) * 8;   // 0,8,...,56
    const size_t base = ((size_t)(b * N_ + n0 + nb + r)) * C_ + h * 64 + cg;
    *(float4*)&Ks[r][cg]     = *(const float4*)&kf[base];
    *(float4*)&Ks[r][cg + 4] = *(const float4*)&kf[base + 4];
    *(float4*)&Vs[r][cg]     = *(const float4*)&vf[base];
    *(float4*)&Vs[r][cg + 4] = *(const float4*)&vf[base + 4];
    __syncthreads();
    #pragma unroll
    for (int kk = 0; kk < 32; ++kk) {
      const float4 a = *(const float4*)&Ks[kk][ty * 4];
      const float4 b = *(const float4*)&Vs[kk][tx * 4];
      const float av[4] = {a.x, a.y, a.z, a.w};
      const float bv[4] = {b.x, b.y, b.z, b.w};
      #pragma unroll
      for (int i = 0; i < 4; ++i)
        #pragma unroll
        for (int j = 0; j < 4; ++j)
          acc[i][j] = fmaf(av[i], bv[j], acc[i][j]);
    }
    __syncthreads();
  }
  #pragma unroll
  for (int i = 0; i < 4; ++i)
    #pragma unroll
    for (int j = 0; j < 4; ++j)
      atomicAdd(&kvm[(bh * 64 + ty * 4 + i) * 64 + tx * 4 + j], acc[i][j]);
}

// ---------------- z[bh][n] = 1/(q[bh][n][:] . ksum[bh][:] + 1e-6) ----------------
__global__ __launch_bounds__(256) void z_kernel(
    const float* __restrict__ qf, const float* __restrict__ ksum, float* __restrict__ zbuf)
{
  const int bh = blockIdx.x, b = bh >> 3, h = bh & 7;
  const int lane = threadIdx.x & 63, wave = threadIdx.x >> 6;
  const int n = blockIdx.y * 4 + wave;
  float v = qf[((size_t)(b * N_ + n)) * C_ + h * 64 + lane] * ksum[bh * 64 + lane];
  #pragma unroll
  for (int off = 32; off > 0; off >>= 1) v += __shfl_xor(v, off);
  if (lane == 0) zbuf[bh * N_ + n] = 1.f / (v + 1e-6f);
}

// ---------------- out[bh][n][d] = z[bh][n] * sum_c q[bh][n][c]*kvm[bh][c][d] ----------------
__global__ __launch_bounds__(256) void attnout_kernel(
    const float* __restrict__ qf, const float* __restrict__ kvm,
    const float* __restrict__ zbuf, float* __restrict__ out)
{
  __shared__ float Qs[64][68];  // [c][row]
  __shared__ float Ms[64][68];  // [c][d]
  const int bh = blockIdx.x, b = bh >> 3, h = bh & 7;
  const int n0 = blockIdx.y * 64;
  const int tid = threadIdx.x;
  {
    const int r  = tid >> 2;         // 0..63
    const int cg = (tid & 3) * 16;   // 0,16,32,48
    #pragma unroll
    for (int u = 0; u < 16; u += 4) {
      const float4 v = *(const float4*)&qf[((size_t)(b * N_ + n0 + r)) * C_ + h * 64 + cg + u];
      Qs[cg + u + 0][r] = v.x;
      Qs[cg + u + 1][r] = v.y;
      Qs[cg + u + 2][r] = v.z;
      Qs[cg + u + 3][r] = v.w;
      *(float4*)&Ms[r][cg + u] = *(const float4*)&kvm[(bh * 64 + r) * 64 + cg + u];
    }
  }
  __syncthreads();
  const int tx = tid & 15, ty = tid >> 4;
  float acc[4][4] = {};
  #pragma unroll
  for (int c = 0; c < 64; ++c) {
    const float4 a = *(const float4*)&Qs[c][ty * 4];
    const float4 b = *(const float4*)&Ms[c][tx * 4];
    const float av[4] = {a.x, a.y, a.z, a.w};
    const float bv[4] = {b.x, b.y, b.z, b.w};
    #pragma unroll
    for (int i = 0; i < 4; ++i)
      #pragma unroll
      for (int j = 0; j < 4; ++j)
        acc[i][j] = fmaf(av[i], bv[j], acc[i][j]);
  }
  #pragma unroll
  for (int i = 0; i < 4; ++i) {
    const int n = n0 + ty * 4 + i;
    const float zv = zbuf[bh * N_ + n];
    *(float4*)&out[((size_t)(b * N_ + n)) * C_ + h * 64 + tx * 4] =
        make_float4(acc[i][0] * zv, acc[i][1] * zv, acc[i][2] * zv, acc[i][3] * zv);
  }
}

// ---------------- depthwise 5x5 SAME conv on q viewed as (bh, hd, 64, 64); out += conv + bias ----------------
__global__ void dwconv_kernel(
    const float* __restrict__ qf, const float* __restrict__ w,
    const float* __restrict__ wb, float* __restrict__ out)
{
  __shared__ float ws_[64 * 25];
  const int tid = threadIdx.y * 64 + threadIdx.x;
  for (int i = tid; i < 64 * 25; i += 256) ws_[i] = w[i];
  __syncthreads();
  const int bh = blockIdx.x, b = bh >> 3, h = bh & 7;
  const int hd = threadIdx.x;                 // 0..63
  const int p  = blockIdx.y * 4 + threadIdx.y;
  const int y = p >> 6, x0 = p & 63;
  float acc = wb[hd];
  #pragma unroll
  for (int ky = 0; ky < 5; ++ky) {
    const int yy = y + ky - 2;
    if (yy < 0 || yy >= 64) continue;
    #pragma unroll
    for (int kx = 0; kx < 5; ++kx) {
      const int xx = x0 + kx - 2;
      if (xx < 0 || xx >= 64) continue;
      acc = fmaf(ws_[hd * 25 + ky * 5 + kx],
                 qf[((size_t)(b * N_ + yy * 64 + xx)) * C_ + h * 64 + hd], acc);
    }
  }
  out[((size_t)(b * N_ + p)) * C_ + h * 64 + hd] += acc;
}

extern "C" void kernel_launch(void* const* d_in, const int* in_sizes, int n_in,
                              void* d_out, int out_size, void* d_ws, size_t ws_size,
                              hipStream_t stream) {
  (void)in_sizes; (void)n_in; (void)out_size; (void)ws_size;
  const float* x     = (const float*)d_in[0];
  const float* Wq    = (const float*)d_in[1];
  const float* Wkv   = (const float*)d_in[2];
  const float* Wp    = (const float*)d_in[3];
  const float* bp    = (const float*)d_in[4];
  const float* sp    = (const float*)d_in[5];
  const float* dwc_w = (const float*)d_in[6];
  const float* dwc_b = (const float*)d_in[7];
  float* out = (float*)d_out;

  char* ws = (char*)d_ws;
  float* qbuf = (float*)ws;                       // 64 MB (focused q)
  float* kout = (float*)(ws + 67108864);          // 64 MB (k, later attention-out)
  float* kvm  = (float*)(ws + 2ull * 67108864);   // 1 MB
  float* ksum = kvm + 64 * 64 * 64;               // 16 KB
  float* zbuf = ksum + 64 * 64;                   // 1 MB
  float* vbuf = out;                              // alias d_out (dead before proj writes)

  const int M = B_ * N_;  // 32768

  // 1) q = relu(x@Wq)+eps
  gemm_tiled<<<dim3(M / 64, C_ / 64), 256, 0, stream>>>(
      x, Wq, nullptr, qbuf, nullptr, M, C_, C_, C_, 1, 0);
  // 2) kv = x@Wkv ; k = relu+eps -> kout ; v -> vbuf(d_out)
  gemm_tiled<<<dim3(M / 64, (2 * C_) / 64), 256, 0, stream>>>(
      x, Wkv, nullptr, kout, vbuf, M, 2 * C_, C_, C_, 1, 0);
  // 3) focus (in-place, row-wise)
  focus_kernel<<<M, 64, 0, stream>>>(qbuf, sp);
  focus_kernel<<<M, 64, 0, stream>>>(kout, sp);
  // 4) zero kvm + ksum (accumulated atomically)
  hipMemsetAsync(kvm, 0, (64 * 64 * 64 + 64 * 64) * sizeof(float), stream);
  // 5) ksum
  ksum_kernel<<<dim3(BH_, 16), 256, 0, stream>>>(kout, ksum);
  // 6) kvm = k^T v per head
  kvm_kernel<<<dim3(BH_, 8), 256, 0, stream>>>(kout, vbuf, kvm);
  // 7) z = 1/(q.ksum + 1e-6)
  z_kernel<<<dim3(BH_, N_ / 4), 256, 0, stream>>>(qbuf, ksum, zbuf);
  // 8) attention out -> kout (k dead now)
  attnout_kernel<<<dim3(BH_, N_ / 64), 256, 0, stream>>>(qbuf, kvm, zbuf, kout);
  // 9) depthwise conv on focused q, += into kout
  dwconv_kernel<<<dim3(BH_, N_ / 4), dim3(64, 4), 0, stream>>>(qbuf, dwc_w, dwc_b, kout);
  // 10) final proj -> d_out
  gemm_tiled<<<dim3(M / 64, C_ / 64), 256, 0, stream>>>(
      kout, Wp, bp, out, nullptr, M, C_, C_, C_, 0, 0);
}

// Round 2
// 875.233 us; speedup vs baseline: 1.6502x; 1.6502x over previous
//
#include <hip/hip_runtime.h>
#include <cstddef>
#include <cstdint>

#define B_ 8
#define N_ 4096
#define C_ 512
#define H_ 8
#define HD_ 64
#define BH_ 64

typedef short  bf16x8 __attribute__((ext_vector_type(8)));
typedef float  f32x4  __attribute__((ext_vector_type(4)));
typedef ushort u16x8  __attribute__((ext_vector_type(8)));

__device__ __forceinline__ float softplusf(float p) {
  return (p > 20.f) ? p : log1pf(expf(p));
}

__device__ __forceinline__ ushort f2bf(float f) {
  union { float f; unsigned u; } c; c.f = f;
  const unsigned r = c.u + 0x7fffu + ((c.u >> 16) & 1u);
  return (ushort)(r >> 16);
}
__device__ __forceinline__ float bf2f(ushort h) {
  union { unsigned u; float f; } c; c.u = ((unsigned)h) << 16;
  return c.f;
}

#define GLOAD16(g, l)                                                        \
  __builtin_amdgcn_global_load_lds(                                          \
      (const __attribute__((address_space(1))) void*)(g),                    \
      (__attribute__((address_space(3))) void*)(l), 16, 0, 0)

// ---------------- fp32 -> bf16 hi/lo split (row-major pass-through) ----------------
__global__ __launch_bounds__(256) void cvt_split(const float* __restrict__ in,
                                                 ushort* __restrict__ hi,
                                                 ushort* __restrict__ lo)
{
  const size_t i = (size_t)blockIdx.x * 256 + threadIdx.x;  // 8 elems per thread
  const float4 a = ((const float4*)in)[i * 2];
  const float4 b = ((const float4*)in)[i * 2 + 1];
  const float f[8] = {a.x, a.y, a.z, a.w, b.x, b.y, b.z, b.w};
  u16x8 h, l;
  #pragma unroll
  for (int j = 0; j < 8; ++j) {
    const ushort hb = f2bf(f[j]);
    h[j] = hb;
    l[j] = f2bf(f[j] - bf2f(hb));
  }
  *(u16x8*)&hi[i * 8] = h;
  *(u16x8*)&lo[i * 8] = l;
}

// ---------------- fp32 KxN weight -> bf16 hi/lo, transposed to NxK ----------------
__global__ __launch_bounds__(256) void cvt_w_t(const float* __restrict__ in,
                                               ushort* __restrict__ hi,
                                               ushort* __restrict__ lo, int Nn)
{
  const int t  = blockIdx.x * 256 + threadIdx.x;  // Nn*64 threads total
  const int n  = t >> 6;
  const int k8 = (t & 63) * 8;
  u16x8 h, l;
  #pragma unroll
  for (int j = 0; j < 8; ++j) {
    const float v = in[(size_t)(k8 + j) * Nn + n];
    const ushort hb = f2bf(v);
    h[j] = hb;
    l[j] = f2bf(v - bf2f(hb));
  }
  *(u16x8*)&hi[(size_t)n * 512 + k8] = h;
  *(u16x8*)&lo[(size_t)n * 512 + k8] = l;
}

// ---------------- split-bf16 MFMA GEMM: out = act(A @ B^T (+bias)) ----------------
// A: M x 512 bf16 (hi/lo, row-major). B: N x 512 bf16 (hi/lo, K-contig "transposed").
// acc = Ah*Bh + Ah*Bl + Al*Bh in fp32 MFMA -> ~fp32 accuracy.
// Tile 128x128, BK=32 (one 16x16x32 MFMA K-step). 4 waves, 64x64 out per wave.
__global__ __launch_bounds__(256) void gemm_mfma_split(
    const ushort* __restrict__ Ah, const ushort* __restrict__ Al,
    const ushort* __restrict__ Bh, const ushort* __restrict__ Bl,
    const float* __restrict__ bias,
    float* __restrict__ out0, float* __restrict__ out1,
    int Nn, int split, int relu0, int relu1)
{
  __shared__ ushort lds[16384];  // AH[4096] AL[4096] BH[4096] BL[4096] (chunks: kb-major)
  const int tid  = threadIdx.x;
  const int row0 = blockIdx.x * 128;
  const int col0 = blockIdx.y * 128;

  const int lane = tid & 63;
  const int li   = lane & 15;
  const int kq   = lane >> 4;                // k-chunk for frags / row-quad for C
  const int wr   = ((tid >> 7) & 1) * 64;    // wave row offset
  const int wc   = ((tid >> 6) & 1) * 64;    // wave col offset
  const int w64  = tid & 192;                // wave-uniform thread base

  f32x4 acc[4][4] = {};

  for (int k0 = 0; k0 < 512; k0 += 32) {
    // ---- stage: 4 tiles (Ah,Al,Bh,Bl) of 128x32 bf16, chunk c -> lds[c*16B]
    #pragma unroll
    for (int half = 0; half < 2; ++half) {
      const int c   = half * 256 + tid;       // chunk id 0..511
      const int cw  = half * 256 + w64;       // wave-uniform chunk base
      const int kb  = c >> 7;                 // 0..3 (8 k-values each)
      const int idx = c & 127;                // row (A) / col (B)
      const size_t gA = (size_t)(row0 + idx) * 512 + k0 + kb * 8;
      const size_t gB = (size_t)(col0 + idx) * 512 + k0 + kb * 8;
      GLOAD16(Ah + gA, &lds[        cw * 8]);
      GLOAD16(Al + gA, &lds[ 4096 + cw * 8]);
      GLOAD16(Bh + gB, &lds[ 8192 + cw * 8]);
      GLOAD16(Bl + gB, &lds[12288 + cw * 8]);
    }
    __syncthreads();  // drains vmcnt, staging visible

    bf16x8 bhv[4], blv[4];
    #pragma unroll
    for (int n = 0; n < 4; ++n) {
      const int off = (kq * 128 + wc + n * 16 + li) * 8;
      bhv[n] = *(const bf16x8*)&lds[ 8192 + off];
      blv[n] = *(const bf16x8*)&lds[12288 + off];
    }
    #pragma unroll
    for (int m = 0; m < 4; ++m) {
      const int off = (kq * 128 + wr + m * 16 + li) * 8;
      const bf16x8 ahm = *(const bf16x8*)&lds[       off];
      const bf16x8 alm = *(const bf16x8*)&lds[4096 + off];
      #pragma unroll
      for (int n = 0; n < 4; ++n) {
        acc[m][n] = __builtin_amdgcn_mfma_f32_16x16x32_bf16(ahm, bhv[n], acc[m][n], 0, 0, 0);
        acc[m][n] = __builtin_amdgcn_mfma_f32_16x16x32_bf16(ahm, blv[n], acc[m][n], 0, 0, 0);
        acc[m][n] = __builtin_amdgcn_mfma_f32_16x16x32_bf16(alm, bhv[n], acc[m][n], 0, 0, 0);
      }
    }
    __syncthreads();  // all reads done before next stage overwrites
  }

  // ---- epilogue: C/D map col=lane&15, row=(lane>>4)*4+reg (verified m89/m91)
  float* dest; int ldd, cbase, relu;
  if (col0 < split) { dest = out0; ldd = split;      cbase = 0;     relu = relu0; }
  else              { dest = out1; ldd = Nn - split; cbase = split; relu = relu1; }
  #pragma unroll
  for (int m = 0; m < 4; ++m) {
    #pragma unroll
    for (int n = 0; n < 4; ++n) {
      const int col = col0 + wc + n * 16 + li;
      const int row = row0 + wr + m * 16 + kq * 4;
      const float bv = bias ? bias[col] : 0.f;
      #pragma unroll
      for (int r = 0; r < 4; ++r) {
        float v = acc[m][n][r] + bv;
        if (relu) v = fmaxf(v, 0.f) + 1e-6f;
        dest[(size_t)(row + r) * ldd + (col - cbase)] = v;
      }
    }
  }
}

// ---------------- focus: t /= softplus(sp); t = t^3 * ||t|| / ||t^3|| ----------------
__global__ __launch_bounds__(64) void focus_kernel(float* __restrict__ t, const float* __restrict__ sp)
{
  const int row = blockIdx.x;
  const int lane = threadIdx.x;
  float* p = t + (size_t)row * C_ + lane * 8;
  const float4 a = *(const float4*)p;
  const float4 b = *(const float4*)(p + 4);
  float tv[8] = {a.x, a.y, a.z, a.w, b.x, b.y, b.z, b.w};
  float s2 = 0.f, s6 = 0.f;
  #pragma unroll
  for (int i = 0; i < 8; ++i) {
    const float sc = softplusf(sp[lane * 8 + i]);
    const float x = tv[i] / sc;
    tv[i] = x;
    const float x3 = x * x * x;
    s2 = fmaf(x, x, s2);
    s6 = fmaf(x3, x3, s6);
  }
  #pragma unroll
  for (int off = 32; off > 0; off >>= 1) {
    s2 += __shfl_xor(s2, off);
    s6 += __shfl_xor(s6, off);
  }
  const float f = sqrtf(s2 / s6);
  float o[8];
  #pragma unroll
  for (int i = 0; i < 8; ++i) o[i] = tv[i] * tv[i] * tv[i] * f;
  *(float4*)p       = make_float4(o[0], o[1], o[2], o[3]);
  *(float4*)(p + 4) = make_float4(o[4], o[5], o[6], o[7]);
}

// ---------------- kvm[bh][c][d] = sum_n k*v ; fused ksum[bh][c] = sum_n k ----------------
__global__ __launch_bounds__(256) void kvm_kernel(
    const float* __restrict__ kf, const float* __restrict__ vf,
    float* __restrict__ kvm, float* __restrict__ ksum)
{
  __shared__ float Ks[32][68];
  __shared__ float Vs[32][68];
  const int bh = blockIdx.x, bb = bh >> 3, h = bh & 7;
  const int n0 = blockIdx.y * 512;
  const int tid = threadIdx.x;
  const int tx = tid & 15, ty = tid >> 4;
  const int r  = tid >> 3;
  const int cg = (tid & 7) * 8;
  float acc[4][4] = {};
  float ks[8] = {};
  for (int nb = 0; nb < 512; nb += 32) {
    const size_t base = ((size_t)(bb * N_ + n0 + nb + r)) * C_ + h * 64 + cg;
    const float4 k0v = *(const float4*)&kf[base];
    const float4 k1v = *(const float4*)&kf[base + 4];
    *(float4*)&Ks[r][cg]     = k0v;
    *(float4*)&Ks[r][cg + 4] = k1v;
    ks[0] += k0v.x; ks[1] += k0v.y; ks[2] += k0v.z; ks[3] += k0v.w;
    ks[4] += k1v.x; ks[5] += k1v.y; ks[6] += k1v.z; ks[7] += k1v.w;
    *(float4*)&Vs[r][cg]     = *(const float4*)&vf[base];
    *(float4*)&Vs[r][cg + 4] = *(const float4*)&vf[base + 4];
    __syncthreads();
    #pragma unroll
    for (int kk = 0; kk < 32; ++kk) {
      const float4 a = *(const float4*)&Ks[kk][ty * 4];
      const float4 c = *(const float4*)&Vs[kk][tx * 4];
      const float av[4] = {a.x, a.y, a.z, a.w};
      const float bv[4] = {c.x, c.y, c.z, c.w};
      #pragma unroll
      for (int i = 0; i < 4; ++i)
        #pragma unroll
        for (int j = 0; j < 4; ++j)
          acc[i][j] = fmaf(av[i], bv[j], acc[i][j]);
    }
    __syncthreads();
  }
  #pragma unroll
  for (int i = 0; i < 4; ++i)
    #pragma unroll
    for (int j = 0; j < 4; ++j)
      atomicAdd(&kvm[(bh * 64 + ty * 4 + i) * 64 + tx * 4 + j], acc[i][j]);
  // fused ksum: wave-reduce lanes with equal (lane&7), then 8 lanes atomically add
  #pragma unroll
  for (int j = 0; j < 8; ++j) {
    float s = ks[j];
    s += __shfl_xor(s, 8);
    s += __shfl_xor(s, 16);
    s += __shfl_xor(s, 32);
    if ((tid & 56) == 0) atomicAdd(&ksum[bh * 64 + cg + j], s);
  }
}

// ---------------- out[bh][n][d] = z * sum_c q*kvm, z fused (= 1/(q.ksum+1e-6)) ----------------
__global__ __launch_bounds__(256) void attnout_kernel(
    const float* __restrict__ qf, const float* __restrict__ kvm,
    const float* __restrict__ ksum, float* __restrict__ out)
{
  __shared__ float Qs[64][68];  // [c][row]
  __shared__ float Ms[64][68];  // [c][d]
  __shared__ float zrow[64];
  const int bh = blockIdx.x, bb = bh >> 3, h = bh & 7;
  const int n0 = blockIdx.y * 64;
  const int tid = threadIdx.x;
  {
    const int r  = tid >> 2;
    const int cg = (tid & 3) * 16;
    #pragma unroll
    for (int u = 0; u < 16; u += 4) {
      const float4 v = *(const float4*)&qf[((size_t)(bb * N_ + n0 + r)) * C_ + h * 64 + cg + u];
      Qs[cg + u + 0][r] = v.x;
      Qs[cg + u + 1][r] = v.y;
      Qs[cg + u + 2][r] = v.z;
      Qs[cg + u + 3][r] = v.w;
      *(float4*)&Ms[r][cg + u] = *(const float4*)&kvm[(bh * 64 + r) * 64 + cg + u];
    }
  }
  __syncthreads();
  // fused z: 4 threads per row, 16 c each, shfl-combine
  {
    const int r  = tid >> 2;
    const int cq = (tid & 3) * 16;
    float p = 0.f;
    #pragma unroll
    for (int u = 0; u < 16; ++u) p = fmaf(Qs[cq + u][r], ksum[bh * 64 + cq + u], p);
    p += __shfl_xor(p, 1);
    p += __shfl_xor(p, 2);
    if ((tid & 3) == 0) zrow[r] = 1.f / (p + 1e-6f);
  }
  const int tx = tid & 15, ty = tid >> 4;
  float acc[4][4] = {};
  #pragma unroll
  for (int c = 0; c < 64; ++c) {
    const float4 a = *(const float4*)&Qs[c][ty * 4];
    const float4 b = *(const float4*)&Ms[c][tx * 4];
    const float av[4] = {a.x, a.y, a.z, a.w};
    const float bv[4] = {b.x, b.y, b.z, b.w};
    #pragma unroll
    for (int i = 0; i < 4; ++i)
      #pragma unroll
      for (int j = 0; j < 4; ++j)
        acc[i][j] = fmaf(av[i], bv[j], acc[i][j]);
  }
  __syncthreads();  // zrow ready
  #pragma unroll
  for (int i = 0; i < 4; ++i) {
    const int n = n0 + ty * 4 + i;
    const float zv = zrow[ty * 4 + i];
    *(float4*)&out[((size_t)(bb * N_ + n)) * C_ + h * 64 + tx * 4] =
        make_float4(acc[i][0] * zv, acc[i][1] * zv, acc[i][2] * zv, acc[i][3] * zv);
  }
}

// ---------------- depthwise 5x5 conv + add attn-out, emit bf16 hi/lo for proj GEMM ----------------
__global__ void dwconv_split(
    const float* __restrict__ qf, const float* __restrict__ w,
    const float* __restrict__ wb, const float* __restrict__ ano,
    ushort* __restrict__ oh, ushort* __restrict__ ol)
{
  __shared__ float ws_[64 * 25];
  const int tid = threadIdx.y * 64 + threadIdx.x;
  for (int i = tid; i < 64 * 25; i += 256) ws_[i] = w[i];
  __syncthreads();
  const int bh = blockIdx.x, bb = bh >> 3, h = bh & 7;
  const int hd = threadIdx.x;
  const int p  = blockIdx.y * 4 + threadIdx.y;
  const int y = p >> 6, x0 = p & 63;
  float acc = wb[hd];
  #pragma unroll
  for (int ky = 0; ky < 5; ++ky) {
    const int yy = y + ky - 2;
    if (yy < 0 || yy >= 64) continue;
    #pragma unroll
    for (int kx = 0; kx < 5; ++kx) {
      const int xx = x0 + kx - 2;
      if (xx < 0 || xx >= 64) continue;
      acc = fmaf(ws_[hd * 25 + ky * 5 + kx],
                 qf[((size_t)(bb * N_ + yy * 64 + xx)) * C_ + h * 64 + hd], acc);
    }
  }
  const size_t idx = ((size_t)(bb * N_ + p)) * C_ + h * 64 + hd;
  const float v = ano[idx] + acc;
  const ushort hb = f2bf(v);
  oh[idx] = hb;
  ol[idx] = f2bf(v - bf2f(hb));
}

extern "C" void kernel_launch(void* const* d_in, const int* in_sizes, int n_in,
                              void* d_out, int out_size, void* d_ws, size_t ws_size,
                              hipStream_t stream) {
  (void)in_sizes; (void)n_in; (void)out_size; (void)ws_size;
  const float* x     = (const float*)d_in[0];
  const float* Wq    = (const float*)d_in[1];
  const float* Wkv   = (const float*)d_in[2];
  const float* Wp    = (const float*)d_in[3];
  const float* bp    = (const float*)d_in[4];
  const float* sp    = (const float*)d_in[5];
  const float* dwc_w = (const float*)d_in[6];
  const float* dwc_b = (const float*)d_in[7];
  float* out = (float*)d_out;

  char* ws = (char*)d_ws;
  ushort* xh   = (ushort*)ws;                        // 32MB; later anoh
  ushort* xl   = (ushort*)(ws + 33554432ull);        // 32MB; later anol
  float*  qbuf = (float*)(ws + 67108864ull);         // 64MB focused q
  float*  kbuf = (float*)(ws + 134217728ull);        // 64MB k; later ano
  char*   w0   = ws + 201326592ull;                  // small buffers @192MB
  ushort* Wqh = (ushort*)w0;
  ushort* Wql = Wqh + 262144;
  ushort* Wkh = Wql + 262144;
  ushort* Wkl = Wkh + 524288;
  ushort* Wph = Wkl + 524288;
  ushort* Wpl = Wph + 262144;
  float*  kvmb = (float*)(w0 + 4194304);             // 1MB
  float*  ksum = kvmb + 262144;                      // 16KB
  float*  vbuf = out;                                // v aliases d_out (dead before proj)
  float*  ano  = kbuf;                               // attn-out aliases k (dead after kvm)

  const int M = B_ * N_;  // 32768

  // 0) bf16 hi/lo splits
  cvt_split<<<8192, 256, 0, stream>>>(x, xh, xl);
  cvt_w_t<<<128, 256, 0, stream>>>(Wq, Wqh, Wql, 512);
  cvt_w_t<<<256, 256, 0, stream>>>(Wkv, Wkh, Wkl, 1024);
  cvt_w_t<<<128, 256, 0, stream>>>(Wp, Wph, Wpl, 512);
  // 1) q = relu(x@Wq)+eps
  gemm_mfma_split<<<dim3(M / 128, 4), 256, 0, stream>>>(
      xh, xl, Wqh, Wql, nullptr, qbuf, nullptr, 512, 512, 1, 0);
  // 2) kv: k (relu+eps) -> kbuf, v -> d_out
  gemm_mfma_split<<<dim3(M / 128, 8), 256, 0, stream>>>(
      xh, xl, Wkh, Wkl, nullptr, kbuf, vbuf, 1024, 512, 1, 0);
  // 3) focus
  focus_kernel<<<M, 64, 0, stream>>>(qbuf, sp);
  focus_kernel<<<M, 64, 0, stream>>>(kbuf, sp);
  // 4) zero kvm + ksum
  hipMemsetAsync(kvmb, 0, (262144 + 4096) * sizeof(float), stream);
  // 5) kvm + fused ksum
  kvm_kernel<<<dim3(BH_, 8), 256, 0, stream>>>(kbuf, vbuf, kvmb, ksum);
  // 6) attention out (fused z) -> ano (=kbuf)
  attnout_kernel<<<dim3(BH_, N_ / 64), 256, 0, stream>>>(qbuf, kvmb, ksum, ano);
  // 7) dwconv + add + bf16-split -> (xh, xl) reused as proj input
  dwconv_split<<<dim3(BH_, N_ / 4), dim3(64, 4), 0, stream>>>(qbuf, dwc_w, dwc_b, ano, xh, xl);
  // 8) final proj -> d_out
  gemm_mfma_split<<<dim3(M / 128, 4), 256, 0, stream>>>(
      xh, xl, Wph, Wpl, bp, out, nullptr, 512, 512, 0, 0);
}

// Round 3
// 648.613 us; speedup vs baseline: 2.2267x; 1.3494x over previous
//
#include <hip/hip_runtime.h>
#include <cstddef>
#include <cstdint>

#define B_ 8
#define N_ 4096
#define C_ 512
#define H_ 8
#define HD_ 64
#define BH_ 64

typedef short  bf16x8 __attribute__((ext_vector_type(8)));
typedef float  f32x4  __attribute__((ext_vector_type(4)));
typedef ushort u16x8  __attribute__((ext_vector_type(8)));

__device__ __forceinline__ float softplusf(float p) {
  return (p > 20.f) ? p : log1pf(expf(p));
}

__device__ __forceinline__ ushort f2bf(float f) {
  union { float f; unsigned u; } c; c.f = f;
  const unsigned r = c.u + 0x7fffu + ((c.u >> 16) & 1u);
  return (ushort)(r >> 16);
}
__device__ __forceinline__ float bf2f(ushort h) {
  union { unsigned u; float f; } c; c.u = ((unsigned)h) << 16;
  return c.f;
}

#define GLOAD16(g, l)                                                        \
  __builtin_amdgcn_global_load_lds(                                          \
      (const __attribute__((address_space(1))) void*)(g),                    \
      (__attribute__((address_space(3))) void*)(l), 16, 0, 0)

// ---------------- sinv[c] = 1/softplus(sp[c]) (one block) ----------------
__global__ void scale_kernel(const float* __restrict__ sp, float* __restrict__ sinv)
{
  const int c = threadIdx.x;
  sinv[c] = 1.f / softplusf(sp[c]);
}

// ---------------- fp32 -> bf16 hi/lo split ----------------
__global__ __launch_bounds__(256) void cvt_split(const float* __restrict__ in,
                                                 ushort* __restrict__ hi,
                                                 ushort* __restrict__ lo)
{
  const size_t i = (size_t)blockIdx.x * 256 + threadIdx.x;  // 8 elems per thread
  const float4 a = ((const float4*)in)[i * 2];
  const float4 b = ((const float4*)in)[i * 2 + 1];
  const float f[8] = {a.x, a.y, a.z, a.w, b.x, b.y, b.z, b.w};
  u16x8 h, l;
  #pragma unroll
  for (int j = 0; j < 8; ++j) {
    const ushort hb = f2bf(f[j]);
    h[j] = hb;
    l[j] = f2bf(f[j] - bf2f(hb));
  }
  *(u16x8*)&hi[i * 8] = h;
  *(u16x8*)&lo[i * 8] = l;
}

// ---------------- fp32 KxN weight -> bf16 hi/lo, transposed to NxK ----------------
__global__ __launch_bounds__(256) void cvt_w_t(const float* __restrict__ in,
                                               ushort* __restrict__ hi,
                                               ushort* __restrict__ lo, int Nn)
{
  const int t  = blockIdx.x * 256 + threadIdx.x;
  const int n  = t >> 6;
  const int k8 = (t & 63) * 8;
  u16x8 h, l;
  #pragma unroll
  for (int j = 0; j < 8; ++j) {
    const float v = in[(size_t)(k8 + j) * Nn + n];
    const ushort hb = f2bf(v);
    h[j] = hb;
    l[j] = f2bf(v - bf2f(hb));
  }
  *(u16x8*)&hi[(size_t)n * 512 + k8] = h;
  *(u16x8*)&lo[(size_t)n * 512 + k8] = l;
}

// ---------------- split-bf16 MFMA GEMM (128x128 tile, BK=32, 4 waves) ----------------
__global__ __launch_bounds__(256) void gemm_mfma_split(
    const ushort* __restrict__ Ah, const ushort* __restrict__ Al,
    const ushort* __restrict__ Bh, const ushort* __restrict__ Bl,
    const float* __restrict__ bias,
    float* __restrict__ out0, float* __restrict__ out1,
    int Nn, int split, int relu0, int relu1)
{
  __shared__ ushort lds[16384];
  const int tid  = threadIdx.x;
  const int row0 = blockIdx.x * 128;
  const int col0 = blockIdx.y * 128;

  const int lane = tid & 63;
  const int li   = lane & 15;
  const int kq   = lane >> 4;
  const int wr   = ((tid >> 7) & 1) * 64;
  const int wc   = ((tid >> 6) & 1) * 64;
  const int w64  = tid & 192;

  f32x4 acc[4][4] = {};

  for (int k0 = 0; k0 < 512; k0 += 32) {
    #pragma unroll
    for (int half = 0; half < 2; ++half) {
      const int c   = half * 256 + tid;
      const int cw  = half * 256 + w64;
      const int kb  = c >> 7;
      const int idx = c & 127;
      const size_t gA = (size_t)(row0 + idx) * 512 + k0 + kb * 8;
      const size_t gB = (size_t)(col0 + idx) * 512 + k0 + kb * 8;
      GLOAD16(Ah + gA, &lds[        cw * 8]);
      GLOAD16(Al + gA, &lds[ 4096 + cw * 8]);
      GLOAD16(Bh + gB, &lds[ 8192 + cw * 8]);
      GLOAD16(Bl + gB, &lds[12288 + cw * 8]);
    }
    __syncthreads();

    bf16x8 bhv[4], blv[4];
    #pragma unroll
    for (int n = 0; n < 4; ++n) {
      const int off = (kq * 128 + wc + n * 16 + li) * 8;
      bhv[n] = *(const bf16x8*)&lds[ 8192 + off];
      blv[n] = *(const bf16x8*)&lds[12288 + off];
    }
    #pragma unroll
    for (int m = 0; m < 4; ++m) {
      const int off = (kq * 128 + wr + m * 16 + li) * 8;
      const bf16x8 ahm = *(const bf16x8*)&lds[       off];
      const bf16x8 alm = *(const bf16x8*)&lds[4096 + off];
      #pragma unroll
      for (int n = 0; n < 4; ++n) {
        acc[m][n] = __builtin_amdgcn_mfma_f32_16x16x32_bf16(ahm, bhv[n], acc[m][n], 0, 0, 0);
        acc[m][n] = __builtin_amdgcn_mfma_f32_16x16x32_bf16(ahm, blv[n], acc[m][n], 0, 0, 0);
        acc[m][n] = __builtin_amdgcn_mfma_f32_16x16x32_bf16(alm, bhv[n], acc[m][n], 0, 0, 0);
      }
    }
    __syncthreads();
  }

  float* dest; int ldd, cbase, relu;
  if (col0 < split) { dest = out0; ldd = split;      cbase = 0;     relu = relu0; }
  else              { dest = out1; ldd = Nn - split; cbase = split; relu = relu1; }
  #pragma unroll
  for (int m = 0; m < 4; ++m) {
    #pragma unroll
    for (int n = 0; n < 4; ++n) {
      const int col = col0 + wc + n * 16 + li;
      const int row = row0 + wr + m * 16 + kq * 4;
      const float bv = bias ? bias[col] : 0.f;
      #pragma unroll
      for (int r = 0; r < 4; ++r) {
        float v = acc[m][n][r] + bv;
        if (relu) v = fmaxf(v, 0.f) + 1e-6f;
        dest[(size_t)(row + r) * ldd + (col - cbase)] = v;
      }
    }
  }
}

// ---------------- focus on q and k in one launch: t *= sinv; t = t^3*||t||/||t^3|| ----------------
__global__ __launch_bounds__(256) void focus2(float* __restrict__ qb, float* __restrict__ kb,
                                              const float* __restrict__ sinv)
{
  const int rid  = blockIdx.x * 4 + (threadIdx.x >> 6);
  const int lane = threadIdx.x & 63;
  float* t = (rid < B_ * N_) ? qb : kb;
  const int row = rid & (B_ * N_ - 1);
  float* p = t + (size_t)row * C_ + lane * 8;
  const float4 a = *(const float4*)p;
  const float4 b = *(const float4*)(p + 4);
  const float4 sa = *(const float4*)&sinv[lane * 8];
  const float4 sb = *(const float4*)&sinv[lane * 8 + 4];
  float tv[8] = {a.x * sa.x, a.y * sa.y, a.z * sa.z, a.w * sa.w,
                 b.x * sb.x, b.y * sb.y, b.z * sb.z, b.w * sb.w};
  float s2 = 0.f, s6 = 0.f;
  #pragma unroll
  for (int i = 0; i < 8; ++i) {
    const float x = tv[i];
    const float x3 = x * x * x;
    s2 = fmaf(x, x, s2);
    s6 = fmaf(x3, x3, s6);
  }
  #pragma unroll
  for (int off = 32; off > 0; off >>= 1) {
    s2 += __shfl_xor(s2, off);
    s6 += __shfl_xor(s6, off);
  }
  const float f = sqrtf(s2 / s6);
  float o[8];
  #pragma unroll
  for (int i = 0; i < 8; ++i) o[i] = tv[i] * tv[i] * tv[i] * f;
  *(float4*)p       = make_float4(o[0], o[1], o[2], o[3]);
  *(float4*)(p + 4) = make_float4(o[4], o[5], o[6], o[7]);
}

// ---------------- kvm[bh][c][d] = sum_n k*v ; fused ksum[bh][c] = sum_n k ----------------
__global__ __launch_bounds__(256) void kvm_kernel(
    const float* __restrict__ kf, const float* __restrict__ vf,
    float* __restrict__ kvm, float* __restrict__ ksum)
{
  __shared__ float Ks[32][68];
  __shared__ float Vs[32][68];
  const int bh = blockIdx.x, bb = bh >> 3, h = bh & 7;
  const int n0 = blockIdx.y * 256;
  const int tid = threadIdx.x;
  const int tx = tid & 15, ty = tid >> 4;
  const int r  = tid >> 3;
  const int cg = (tid & 7) * 8;
  float acc[4][4] = {};
  float ks[8] = {};
  for (int nb = 0; nb < 256; nb += 32) {
    const size_t base = ((size_t)(bb * N_ + n0 + nb + r)) * C_ + h * 64 + cg;
    const float4 k0v = *(const float4*)&kf[base];
    const float4 k1v = *(const float4*)&kf[base + 4];
    *(float4*)&Ks[r][cg]     = k0v;
    *(float4*)&Ks[r][cg + 4] = k1v;
    ks[0] += k0v.x; ks[1] += k0v.y; ks[2] += k0v.z; ks[3] += k0v.w;
    ks[4] += k1v.x; ks[5] += k1v.y; ks[6] += k1v.z; ks[7] += k1v.w;
    *(float4*)&Vs[r][cg]     = *(const float4*)&vf[base];
    *(float4*)&Vs[r][cg + 4] = *(const float4*)&vf[base + 4];
    __syncthreads();
    #pragma unroll
    for (int kk = 0; kk < 32; ++kk) {
      const float4 a = *(const float4*)&Ks[kk][ty * 4];
      const float4 c = *(const float4*)&Vs[kk][tx * 4];
      const float av[4] = {a.x, a.y, a.z, a.w};
      const float bv[4] = {c.x, c.y, c.z, c.w};
      #pragma unroll
      for (int i = 0; i < 4; ++i)
        #pragma unroll
        for (int j = 0; j < 4; ++j)
          acc[i][j] = fmaf(av[i], bv[j], acc[i][j]);
    }
    __syncthreads();
  }
  #pragma unroll
  for (int i = 0; i < 4; ++i)
    #pragma unroll
    for (int j = 0; j < 4; ++j)
      atomicAdd(&kvm[(bh * 64 + ty * 4 + i) * 64 + tx * 4 + j], acc[i][j]);
  #pragma unroll
  for (int j = 0; j < 8; ++j) {
    float s = ks[j];
    s += __shfl_xor(s, 8);
    s += __shfl_xor(s, 16);
    s += __shfl_xor(s, 32);
    if ((tid & 56) == 0) atomicAdd(&ksum[bh * 64 + cg + j], s);
  }
}

// ---------------- out[bh][n][d] = z * sum_c q*kvm, z fused ----------------
__global__ __launch_bounds__(256) void attnout_kernel(
    const float* __restrict__ qf, const float* __restrict__ kvm,
    const float* __restrict__ ksum, float* __restrict__ out)
{
  __shared__ float Qs[64][68];
  __shared__ float Ms[64][68];
  __shared__ float zrow[64];
  const int bh = blockIdx.x, bb = bh >> 3, h = bh & 7;
  const int n0 = blockIdx.y * 64;
  const int tid = threadIdx.x;
  {
    const int r  = tid >> 2;
    const int cg = (tid & 3) * 16;
    #pragma unroll
    for (int u = 0; u < 16; u += 4) {
      const float4 v = *(const float4*)&qf[((size_t)(bb * N_ + n0 + r)) * C_ + h * 64 + cg + u];
      Qs[cg + u + 0][r] = v.x;
      Qs[cg + u + 1][r] = v.y;
      Qs[cg + u + 2][r] = v.z;
      Qs[cg + u + 3][r] = v.w;
      *(float4*)&Ms[r][cg + u] = *(const float4*)&kvm[(bh * 64 + r) * 64 + cg + u];
    }
  }
  __syncthreads();
  {
    const int r  = tid >> 2;
    const int cq = (tid & 3) * 16;
    float p = 0.f;
    #pragma unroll
    for (int u = 0; u < 16; ++u) p = fmaf(Qs[cq + u][r], ksum[bh * 64 + cq + u], p);
    p += __shfl_xor(p, 1);
    p += __shfl_xor(p, 2);
    if ((tid & 3) == 0) zrow[r] = 1.f / (p + 1e-6f);
  }
  const int tx = tid & 15, ty = tid >> 4;
  float acc[4][4] = {};
  #pragma unroll
  for (int c = 0; c < 64; ++c) {
    const float4 a = *(const float4*)&Qs[c][ty * 4];
    const float4 b = *(const float4*)&Ms[c][tx * 4];
    const float av[4] = {a.x, a.y, a.z, a.w};
    const float bv[4] = {b.x, b.y, b.z, b.w};
    #pragma unroll
    for (int i = 0; i < 4; ++i)
      #pragma unroll
      for (int j = 0; j < 4; ++j)
        acc[i][j] = fmaf(av[i], bv[j], acc[i][j]);
  }
  __syncthreads();
  #pragma unroll
  for (int i = 0; i < 4; ++i) {
    const int n = n0 + ty * 4 + i;
    const float zv = zrow[ty * 4 + i];
    *(float4*)&out[((size_t)(bb * N_ + n)) * C_ + h * 64 + tx * 4] =
        make_float4(acc[i][0] * zv, acc[i][1] * zv, acc[i][2] * zv, acc[i][3] * zv);
  }
}

// ---------------- depthwise 5x5 conv, register-rolling: 8 y-outputs per thread ----------------
// thread -> (hd, x); issues 12 unconditional clamped loads per kx (branchless, high ILP)
__global__ __launch_bounds__(256) void dwconv_split(
    const float* __restrict__ qf, const float* __restrict__ w,
    const float* __restrict__ wb, const float* __restrict__ ano,
    ushort* __restrict__ oh, ushort* __restrict__ ol)
{
  __shared__ float ws_[64 * 25];
  const int tid = threadIdx.x;
  for (int i = tid; i < 64 * 25; i += 256) ws_[i] = w[i];
  __syncthreads();

  const int bh = blockIdx.x, bb = bh >> 3, h = bh & 7;
  const int hd = tid & 63;
  const int s  = blockIdx.y * 4 + (tid >> 6);  // 0..511
  const int x  = s & 63;
  const int y0 = (s >> 6) * 8;

  float wreg[25];
  #pragma unroll
  for (int i = 0; i < 25; ++i) wreg[i] = ws_[hd * 25 + i];

  float acc[8];
  const float bias = wb[hd];
  #pragma unroll
  for (int j = 0; j < 8; ++j) acc[j] = bias;

  const float* base = qf + (size_t)bb * N_ * C_ + h * 64 + hd;
  #pragma unroll
  for (int kx = 0; kx < 5; ++kx) {
    const int xx  = x + kx - 2;
    const bool xok = (unsigned)xx < 64u;
    const int xxc = min(max(xx, 0), 63);
    float col[12];
    #pragma unroll
    for (int r = 0; r < 12; ++r) {
      const int yy  = y0 + r - 2;
      const bool ok = xok && ((unsigned)yy < 64u);
      const int yyc = min(max(yy, 0), 63);
      const float v = base[(size_t)(yyc * 64 + xxc) * C_];
      col[r] = ok ? v : 0.f;
    }
    #pragma unroll
    for (int ky = 0; ky < 5; ++ky) {
      const float wv = wreg[ky * 5 + kx];
      #pragma unroll
      for (int j = 0; j < 8; ++j)
        acc[j] = fmaf(wv, col[j + ky], acc[j]);
    }
  }

  #pragma unroll
  for (int j = 0; j < 8; ++j) {
    const int p = (y0 + j) * 64 + x;
    const size_t idx = ((size_t)(bb * N_ + p)) * C_ + h * 64 + hd;
    const float v = ano[idx] + acc[j];
    const ushort hb = f2bf(v);
    oh[idx] = hb;
    ol[idx] = f2bf(v - bf2f(hb));
  }
}

extern "C" void kernel_launch(void* const* d_in, const int* in_sizes, int n_in,
                              void* d_out, int out_size, void* d_ws, size_t ws_size,
                              hipStream_t stream) {
  (void)in_sizes; (void)n_in; (void)out_size; (void)ws_size;
  const float* x     = (const float*)d_in[0];
  const float* Wq    = (const float*)d_in[1];
  const float* Wkv   = (const float*)d_in[2];
  const float* Wp    = (const float*)d_in[3];
  const float* bp    = (const float*)d_in[4];
  const float* sp    = (const float*)d_in[5];
  const float* dwc_w = (const float*)d_in[6];
  const float* dwc_b = (const float*)d_in[7];
  float* out = (float*)d_out;

  char* ws = (char*)d_ws;
  ushort* xh   = (ushort*)ws;                        // 32MB; later proj-in hi
  ushort* xl   = (ushort*)(ws + 33554432ull);        // 32MB; later proj-in lo
  float*  qbuf = (float*)(ws + 67108864ull);         // 64MB focused q
  float*  kbuf = (float*)(ws + 134217728ull);        // 64MB k; later ano
  char*   w0   = ws + 201326592ull;
  ushort* Wqh = (ushort*)w0;
  ushort* Wql = Wqh + 262144;
  ushort* Wkh = Wql + 262144;
  ushort* Wkl = Wkh + 524288;
  ushort* Wph = Wkl + 524288;
  ushort* Wpl = Wph + 262144;
  float*  kvmb = (float*)(w0 + 4194304);             // 1MB
  float*  ksum = kvmb + 262144;                      // 16KB
  float*  sinv = ksum + 4096;                        // 2KB
  float*  vbuf = out;                                // v aliases d_out
  float*  ano  = kbuf;                               // attn-out aliases k

  const int M = B_ * N_;  // 32768

  scale_kernel<<<1, 512, 0, stream>>>(sp, sinv);
  cvt_split<<<8192, 256, 0, stream>>>(x, xh, xl);
  cvt_w_t<<<128, 256, 0, stream>>>(Wq, Wqh, Wql, 512);
  cvt_w_t<<<256, 256, 0, stream>>>(Wkv, Wkh, Wkl, 1024);
  cvt_w_t<<<128, 256, 0, stream>>>(Wp, Wph, Wpl, 512);
  // q = relu(x@Wq)+eps
  gemm_mfma_split<<<dim3(M / 128, 4), 256, 0, stream>>>(
      xh, xl, Wqh, Wql, nullptr, qbuf, nullptr, 512, 512, 1, 0);
  // kv: k -> kbuf, v -> d_out
  gemm_mfma_split<<<dim3(M / 128, 8), 256, 0, stream>>>(
      xh, xl, Wkh, Wkl, nullptr, kbuf, vbuf, 1024, 512, 1, 0);
  // focus both buffers in one launch
  focus2<<<2 * M / 4, 256, 0, stream>>>(qbuf, kbuf, sinv);
  hipMemsetAsync(kvmb, 0, (262144 + 4096) * sizeof(float), stream);
  kvm_kernel<<<dim3(BH_, 16), 256, 0, stream>>>(kbuf, vbuf, kvmb, ksum);
  attnout_kernel<<<dim3(BH_, N_ / 64), 256, 0, stream>>>(qbuf, kvmb, ksum, ano);
  dwconv_split<<<dim3(BH_, 128), 256, 0, stream>>>(qbuf, dwc_w, dwc_b, ano, xh, xl);
  gemm_mfma_split<<<dim3(M / 128, 4), 256, 0, stream>>>(
      xh, xl, Wph, Wpl, bp, out, nullptr, 512, 512, 0, 0);
}

// Round 4
// 619.645 us; speedup vs baseline: 2.3308x; 1.0468x over previous
//
#include <hip/hip_runtime.h>
#include <cstddef>
#include <cstdint>

#define B_ 8
#define N_ 4096
#define C_ 512
#define H_ 8
#define HD_ 64
#define BH_ 64

typedef short  bf16x8 __attribute__((ext_vector_type(8)));
typedef float  f32x4  __attribute__((ext_vector_type(4)));
typedef ushort u16x8  __attribute__((ext_vector_type(8)));

__device__ __forceinline__ float softplusf(float p) {
  return (p > 20.f) ? p : log1pf(expf(p));
}

__device__ __forceinline__ ushort f2bf(float f) {
  union { float f; unsigned u; } c; c.f = f;
  const unsigned r = c.u + 0x7fffu + ((c.u >> 16) & 1u);
  return (ushort)(r >> 16);
}
__device__ __forceinline__ float bf2f(ushort h) {
  union { unsigned u; float f; } c; c.u = ((unsigned)h) << 16;
  return c.f;
}

#define GLOAD16(g, l)                                                        \
  __builtin_amdgcn_global_load_lds(                                          \
      (const __attribute__((address_space(1))) void*)(g),                    \
      (__attribute__((address_space(3))) void*)(l), 16, 0, 0)

// ---------------- sinv[c] = 1/softplus(sp[c]) ----------------
__global__ void scale_kernel(const float* __restrict__ sp, float* __restrict__ sinv)
{
  const int c = threadIdx.x;
  sinv[c] = 1.f / softplusf(sp[c]);
}

// ---------------- fp32 -> bf16 hi/lo split ----------------
__global__ __launch_bounds__(256) void cvt_split(const float* __restrict__ in,
                                                 ushort* __restrict__ hi,
                                                 ushort* __restrict__ lo)
{
  const size_t i = (size_t)blockIdx.x * 256 + threadIdx.x;
  const float4 a = ((const float4*)in)[i * 2];
  const float4 b = ((const float4*)in)[i * 2 + 1];
  const float f[8] = {a.x, a.y, a.z, a.w, b.x, b.y, b.z, b.w};
  u16x8 h, l;
  #pragma unroll
  for (int j = 0; j < 8; ++j) {
    const ushort hb = f2bf(f[j]);
    h[j] = hb;
    l[j] = f2bf(f[j] - bf2f(hb));
  }
  *(u16x8*)&hi[i * 8] = h;
  *(u16x8*)&lo[i * 8] = l;
}

// ---------------- fp32 KxN weight -> bf16 hi/lo, transposed to NxK ----------------
__global__ __launch_bounds__(256) void cvt_w_t(const float* __restrict__ in,
                                               ushort* __restrict__ hi,
                                               ushort* __restrict__ lo, int Nn)
{
  const int t  = blockIdx.x * 256 + threadIdx.x;
  const int n  = t >> 6;
  const int k8 = (t & 63) * 8;
  u16x8 h, l;
  #pragma unroll
  for (int j = 0; j < 8; ++j) {
    const float v = in[(size_t)(k8 + j) * Nn + n];
    const ushort hb = f2bf(v);
    h[j] = hb;
    l[j] = f2bf(v - bf2f(hb));
  }
  *(u16x8*)&hi[(size_t)n * 512 + k8] = h;
  *(u16x8*)&lo[(size_t)n * 512 + k8] = l;
}

// ---------------- split-bf16 MFMA GEMM, 2-phase double-buffered prefetch ----------------
// A: M x 512 (hi/lo). B: ncolb*128 x 512 K-contig (hi/lo). Out cols routed 3-way.
// 128x128 tile, BK=32, 4 waves. XCD-chunked swizzle: xcd owns 32 row-blocks, col-fastest.
__global__ __launch_bounds__(256) void gemm_mfma_split(
    const ushort* __restrict__ Ah, const ushort* __restrict__ Al,
    const ushort* __restrict__ Bh, const ushort* __restrict__ Bl,
    const float* __restrict__ bias,
    float* __restrict__ out0, float* __restrict__ out1, float* __restrict__ out2,
    int ncolb, int s1, int s2, int r0, int r1, int r2)
{
  __shared__ ushort lds[2][16384];  // per buf: AH[4096] AL[4096] BH[4096] BL[4096]
  const int tid = threadIdx.x;
  const int bid = blockIdx.x;
  const int loc = bid >> 3;
  const int xcd = bid & 7;
  const int row0 = ((xcd << 5) + loc / ncolb) * 128;
  const int col0 = (loc % ncolb) * 128;

  const int lane = tid & 63;
  const int li   = lane & 15;
  const int kq   = lane >> 4;
  const int wr   = ((tid >> 7) & 1) * 64;
  const int wc   = ((tid >> 6) & 1) * 64;
  const int w64  = tid & 192;

  f32x4 acc[4][4] = {};

  auto STAGE = [&](int buf, int k0) {
    ushort* l = &lds[buf][0];
    #pragma unroll
    for (int half = 0; half < 2; ++half) {
      const int c   = half * 256 + tid;
      const int cw  = half * 256 + w64;
      const int kb  = c >> 7;
      const int idx = c & 127;
      const size_t gA = (size_t)(row0 + idx) * 512 + k0 + kb * 8;
      const size_t gB = (size_t)(col0 + idx) * 512 + k0 + kb * 8;
      GLOAD16(Ah + gA, &l[        cw * 8]);
      GLOAD16(Al + gA, &l[ 4096 + cw * 8]);
      GLOAD16(Bh + gB, &l[ 8192 + cw * 8]);
      GLOAD16(Bl + gB, &l[12288 + cw * 8]);
    }
  };

  auto COMPUTE = [&](int buf) {
    const ushort* l = &lds[buf][0];
    bf16x8 bhv[4], blv[4];
    #pragma unroll
    for (int n = 0; n < 4; ++n) {
      const int off = (kq * 128 + wc + n * 16 + li) * 8;
      bhv[n] = *(const bf16x8*)&l[ 8192 + off];
      blv[n] = *(const bf16x8*)&l[12288 + off];
    }
    __builtin_amdgcn_s_setprio(1);
    #pragma unroll
    for (int m = 0; m < 4; ++m) {
      const int off = (kq * 128 + wr + m * 16 + li) * 8;
      const bf16x8 ahm = *(const bf16x8*)&l[       off];
      const bf16x8 alm = *(const bf16x8*)&l[4096 + off];
      #pragma unroll
      for (int n = 0; n < 4; ++n) {
        acc[m][n] = __builtin_amdgcn_mfma_f32_16x16x32_bf16(ahm, bhv[n], acc[m][n], 0, 0, 0);
        acc[m][n] = __builtin_amdgcn_mfma_f32_16x16x32_bf16(ahm, blv[n], acc[m][n], 0, 0, 0);
        acc[m][n] = __builtin_amdgcn_mfma_f32_16x16x32_bf16(alm, bhv[n], acc[m][n], 0, 0, 0);
      }
    }
    __builtin_amdgcn_s_setprio(0);
  };

  // prologue
  STAGE(0, 0);
  __syncthreads();
  // main: stage next (other buf) BEFORE compute of current; one barrier per K-step.
  // The barrier's vmcnt(0) drain lands after the 48-MFMA cluster -> latency hidden.
  #pragma unroll 1
  for (int t = 0; t < 7; ++t) {
    STAGE(1, (2 * t + 1) * 32);
    COMPUTE(0);
    __syncthreads();
    STAGE(0, (2 * t + 2) * 32);
    COMPUTE(1);
    __syncthreads();
  }
  STAGE(1, 480);
  COMPUTE(0);
  __syncthreads();
  COMPUTE(1);

  // epilogue: C/D map col=lane&15, row=(lane>>4)*4+reg
  float* dest; int cbase, relu;
  if (col0 < s1)      { dest = out0; cbase = 0;  relu = r0; }
  else if (col0 < s2) { dest = out1; cbase = s1; relu = r1; }
  else                { dest = out2; cbase = s2; relu = r2; }
  #pragma unroll
  for (int m = 0; m < 4; ++m) {
    #pragma unroll
    for (int n = 0; n < 4; ++n) {
      const int col = col0 + wc + n * 16 + li;
      const int row = row0 + wr + m * 16 + kq * 4;
      const float bv = bias ? bias[col] : 0.f;
      #pragma unroll
      for (int r = 0; r < 4; ++r) {
        float v = acc[m][n][r] + bv;
        if (relu) v = fmaxf(v, 0.f) + 1e-6f;
        dest[(size_t)(row + r) * 512 + (col - cbase)] = v;
      }
    }
  }
}

// ---------------- focus on q and k in one launch ----------------
__global__ __launch_bounds__(256) void focus2(float* __restrict__ qb, float* __restrict__ kb,
                                              const float* __restrict__ sinv)
{
  const int rid  = blockIdx.x * 4 + (threadIdx.x >> 6);
  const int lane = threadIdx.x & 63;
  float* t = (rid < B_ * N_) ? qb : kb;
  const int row = rid & (B_ * N_ - 1);
  float* p = t + (size_t)row * C_ + lane * 8;
  const float4 a = *(const float4*)p;
  const float4 b = *(const float4*)(p + 4);
  const float4 sa = *(const float4*)&sinv[lane * 8];
  const float4 sb = *(const float4*)&sinv[lane * 8 + 4];
  float tv[8] = {a.x * sa.x, a.y * sa.y, a.z * sa.z, a.w * sa.w,
                 b.x * sb.x, b.y * sb.y, b.z * sb.z, b.w * sb.w};
  float s2 = 0.f, s6 = 0.f;
  #pragma unroll
  for (int i = 0; i < 8; ++i) {
    const float x = tv[i];
    const float x3 = x * x * x;
    s2 = fmaf(x, x, s2);
    s6 = fmaf(x3, x3, s6);
  }
  #pragma unroll
  for (int off = 32; off > 0; off >>= 1) {
    s2 += __shfl_xor(s2, off);
    s6 += __shfl_xor(s6, off);
  }
  const float f = sqrtf(s2 / s6);
  float o[8];
  #pragma unroll
  for (int i = 0; i < 8; ++i) o[i] = tv[i] * tv[i] * tv[i] * f;
  *(float4*)p       = make_float4(o[0], o[1], o[2], o[3]);
  *(float4*)(p + 4) = make_float4(o[4], o[5], o[6], o[7]);
}

// ---------------- kvm[bh][c][d] = sum_n k*v ; fused ksum ----------------
__global__ __launch_bounds__(256) void kvm_kernel(
    const float* __restrict__ kf, const float* __restrict__ vf,
    float* __restrict__ kvm, float* __restrict__ ksum)
{
  __shared__ float Ks[32][68];
  __shared__ float Vs[32][68];
  const int bh = blockIdx.x, bb = bh >> 3, h = bh & 7;
  const int n0 = blockIdx.y * 256;
  const int tid = threadIdx.x;
  const int tx = tid & 15, ty = tid >> 4;
  const int r  = tid >> 3;
  const int cg = (tid & 7) * 8;
  float acc[4][4] = {};
  float ks[8] = {};
  for (int nb = 0; nb < 256; nb += 32) {
    const size_t base = ((size_t)(bb * N_ + n0 + nb + r)) * C_ + h * 64 + cg;
    const float4 k0v = *(const float4*)&kf[base];
    const float4 k1v = *(const float4*)&kf[base + 4];
    *(float4*)&Ks[r][cg]     = k0v;
    *(float4*)&Ks[r][cg + 4] = k1v;
    ks[0] += k0v.x; ks[1] += k0v.y; ks[2] += k0v.z; ks[3] += k0v.w;
    ks[4] += k1v.x; ks[5] += k1v.y; ks[6] += k1v.z; ks[7] += k1v.w;
    *(float4*)&Vs[r][cg]     = *(const float4*)&vf[base];
    *(float4*)&Vs[r][cg + 4] = *(const float4*)&vf[base + 4];
    __syncthreads();
    #pragma unroll
    for (int kk = 0; kk < 32; ++kk) {
      const float4 a = *(const float4*)&Ks[kk][ty * 4];
      const float4 c = *(const float4*)&Vs[kk][tx * 4];
      const float av[4] = {a.x, a.y, a.z, a.w};
      const float bv[4] = {c.x, c.y, c.z, c.w};
      #pragma unroll
      for (int i = 0; i < 4; ++i)
        #pragma unroll
        for (int j = 0; j < 4; ++j)
          acc[i][j] = fmaf(av[i], bv[j], acc[i][j]);
    }
    __syncthreads();
  }
  #pragma unroll
  for (int i = 0; i < 4; ++i)
    #pragma unroll
    for (int j = 0; j < 4; ++j)
      atomicAdd(&kvm[(bh * 64 + ty * 4 + i) * 64 + tx * 4 + j], acc[i][j]);
  #pragma unroll
  for (int j = 0; j < 8; ++j) {
    float s = ks[j];
    s += __shfl_xor(s, 8);
    s += __shfl_xor(s, 16);
    s += __shfl_xor(s, 32);
    if ((tid & 56) == 0) atomicAdd(&ksum[bh * 64 + cg + j], s);
  }
}

// ---------------- out = z * (q @ kvm), z fused ----------------
__global__ __launch_bounds__(256) void attnout_kernel(
    const float* __restrict__ qf, const float* __restrict__ kvm,
    const float* __restrict__ ksum, float* __restrict__ out)
{
  __shared__ float Qs[64][68];
  __shared__ float Ms[64][68];
  __shared__ float zrow[64];
  const int bh = blockIdx.x, bb = bh >> 3, h = bh & 7;
  const int n0 = blockIdx.y * 64;
  const int tid = threadIdx.x;
  {
    const int r  = tid >> 2;
    const int cg = (tid & 3) * 16;
    #pragma unroll
    for (int u = 0; u < 16; u += 4) {
      const float4 v = *(const float4*)&qf[((size_t)(bb * N_ + n0 + r)) * C_ + h * 64 + cg + u];
      Qs[cg + u + 0][r] = v.x;
      Qs[cg + u + 1][r] = v.y;
      Qs[cg + u + 2][r] = v.z;
      Qs[cg + u + 3][r] = v.w;
      *(float4*)&Ms[r][cg + u] = *(const float4*)&kvm[(bh * 64 + r) * 64 + cg + u];
    }
  }
  __syncthreads();
  {
    const int r  = tid >> 2;
    const int cq = (tid & 3) * 16;
    float p = 0.f;
    #pragma unroll
    for (int u = 0; u < 16; ++u) p = fmaf(Qs[cq + u][r], ksum[bh * 64 + cq + u], p);
    p += __shfl_xor(p, 1);
    p += __shfl_xor(p, 2);
    if ((tid & 3) == 0) zrow[r] = 1.f / (p + 1e-6f);
  }
  const int tx = tid & 15, ty = tid >> 4;
  float acc[4][4] = {};
  #pragma unroll
  for (int c = 0; c < 64; ++c) {
    const float4 a = *(const float4*)&Qs[c][ty * 4];
    const float4 b = *(const float4*)&Ms[c][tx * 4];
    const float av[4] = {a.x, a.y, a.z, a.w};
    const float bv[4] = {b.x, b.y, b.z, b.w};
    #pragma unroll
    for (int i = 0; i < 4; ++i)
      #pragma unroll
      for (int j = 0; j < 4; ++j)
        acc[i][j] = fmaf(av[i], bv[j], acc[i][j]);
  }
  __syncthreads();
  #pragma unroll
  for (int i = 0; i < 4; ++i) {
    const int n = n0 + ty * 4 + i;
    const float zv = zrow[ty * 4 + i];
    *(float4*)&out[((size_t)(bb * N_ + n)) * C_ + h * 64 + tx * 4] =
        make_float4(acc[i][0] * zv, acc[i][1] * zv, acc[i][2] * zv, acc[i][3] * zv);
  }
}

// ---------------- depthwise 5x5 conv, register-rolling, emits bf16 hi/lo proj input ----------------
__global__ __launch_bounds__(256) void dwconv_split(
    const float* __restrict__ qf, const float* __restrict__ w,
    const float* __restrict__ wb, const float* __restrict__ ano,
    ushort* __restrict__ oh, ushort* __restrict__ ol)
{
  __shared__ float ws_[64 * 25];
  const int tid = threadIdx.x;
  for (int i = tid; i < 64 * 25; i += 256) ws_[i] = w[i];
  __syncthreads();

  const int bh = blockIdx.x, bb = bh >> 3, h = bh & 7;
  const int hd = tid & 63;
  const int s  = blockIdx.y * 4 + (tid >> 6);
  const int x  = s & 63;
  const int y0 = (s >> 6) * 8;

  float wreg[25];
  #pragma unroll
  for (int i = 0; i < 25; ++i) wreg[i] = ws_[hd * 25 + i];

  float acc[8];
  const float bias = wb[hd];
  #pragma unroll
  for (int j = 0; j < 8; ++j) acc[j] = bias;

  const float* base = qf + (size_t)bb * N_ * C_ + h * 64 + hd;
  #pragma unroll
  for (int kx = 0; kx < 5; ++kx) {
    const int xx  = x + kx - 2;
    const bool xok = (unsigned)xx < 64u;
    const int xxc = min(max(xx, 0), 63);
    float col[12];
    #pragma unroll
    for (int r = 0; r < 12; ++r) {
      const int yy  = y0 + r - 2;
      const bool ok = xok && ((unsigned)yy < 64u);
      const int yyc = min(max(yy, 0), 63);
      const float v = base[(size_t)(yyc * 64 + xxc) * C_];
      col[r] = ok ? v : 0.f;
    }
    #pragma unroll
    for (int ky = 0; ky < 5; ++ky) {
      const float wv = wreg[ky * 5 + kx];
      #pragma unroll
      for (int j = 0; j < 8; ++j)
        acc[j] = fmaf(wv, col[j + ky], acc[j]);
    }
  }

  #pragma unroll
  for (int j = 0; j < 8; ++j) {
    const int p = (y0 + j) * 64 + x;
    const size_t idx = ((size_t)(bb * N_ + p)) * C_ + h * 64 + hd;
    const float v = ano[idx] + acc[j];
    const ushort hb = f2bf(v);
    oh[idx] = hb;
    ol[idx] = f2bf(v - bf2f(hb));
  }
}

extern "C" void kernel_launch(void* const* d_in, const int* in_sizes, int n_in,
                              void* d_out, int out_size, void* d_ws, size_t ws_size,
                              hipStream_t stream) {
  (void)in_sizes; (void)n_in; (void)out_size; (void)ws_size;
  const float* x     = (const float*)d_in[0];
  const float* Wq    = (const float*)d_in[1];
  const float* Wkv   = (const float*)d_in[2];
  const float* Wp    = (const float*)d_in[3];
  const float* bp    = (const float*)d_in[4];
  const float* sp    = (const float*)d_in[5];
  const float* dwc_w = (const float*)d_in[6];
  const float* dwc_b = (const float*)d_in[7];
  float* out = (float*)d_out;

  char* ws = (char*)d_ws;
  ushort* xh   = (ushort*)ws;                        // 32MB; later proj-in hi
  ushort* xl   = (ushort*)(ws + 33554432ull);        // 32MB; later proj-in lo
  float*  qbuf = (float*)(ws + 67108864ull);         // 64MB focused q
  float*  kbuf = (float*)(ws + 134217728ull);        // 64MB k; later ano
  char*   w0   = ws + 201326592ull;
  ushort* Bh  = (ushort*)w0;                         // 1536x512 fused [Wq|Wkv]^T hi
  ushort* Bl  = Bh + 786432;                         // 1536x512 lo
  ushort* Wph = Bl + 786432;                         // 512x512
  ushort* Wpl = Wph + 262144;
  float*  kvmb = (float*)(Wpl + 262144);             // 1MB
  float*  ksum = kvmb + 262144;                      // 16KB
  float*  sinv = ksum + 4096;                        // 2KB
  float*  vbuf = out;                                // v aliases d_out
  float*  ano  = kbuf;                               // attn-out aliases k

  const int M = B_ * N_;  // 32768

  scale_kernel<<<1, 512, 0, stream>>>(sp, sinv);
  cvt_split<<<8192, 256, 0, stream>>>(x, xh, xl);
  cvt_w_t<<<128, 256, 0, stream>>>(Wq, Bh, Bl, 512);
  cvt_w_t<<<256, 256, 0, stream>>>(Wkv, Bh + 262144, Bl + 262144, 1024);
  cvt_w_t<<<128, 256, 0, stream>>>(Wp, Wph, Wpl, 512);
  // fused q|k|v GEMM: cols [0,512)->q relu, [512,1024)->k relu, [1024,1536)->v
  gemm_mfma_split<<<256 * 12, 256, 0, stream>>>(
      xh, xl, Bh, Bl, nullptr, qbuf, kbuf, vbuf, 12, 512, 1024, 1, 1, 0);
  focus2<<<2 * M / 4, 256, 0, stream>>>(qbuf, kbuf, sinv);
  hipMemsetAsync(kvmb, 0, (262144 + 4096) * sizeof(float), stream);
  kvm_kernel<<<dim3(BH_, 16), 256, 0, stream>>>(kbuf, vbuf, kvmb, ksum);
  attnout_kernel<<<dim3(BH_, N_ / 64), 256, 0, stream>>>(qbuf, kvmb, ksum, ano);
  dwconv_split<<<dim3(BH_, 128), 256, 0, stream>>>(qbuf, dwc_w, dwc_b, ano, xh, xl);
  // proj
  gemm_mfma_split<<<256 * 4, 256, 0, stream>>>(
      xh, xl, Wph, Wpl, bp, out, out, out, 4, 512, 512, 0, 0, 0);
}

// Round 5
// 524.160 us; speedup vs baseline: 2.7554x; 1.1822x over previous
//
#include <hip/hip_runtime.h>
#include <cstddef>
#include <cstdint>

#define B_ 8
#define N_ 4096
#define C_ 512
#define H_ 8
#define HD_ 64
#define BH_ 64

typedef short  bf16x8 __attribute__((ext_vector_type(8)));
typedef float  f32x4  __attribute__((ext_vector_type(4)));
typedef ushort u16x8  __attribute__((ext_vector_type(8)));

__device__ __forceinline__ float softplusf(float p) {
  return (p > 20.f) ? p : log1pf(expf(p));
}

__device__ __forceinline__ ushort f2bf(float f) {
  union { float f; unsigned u; } c; c.f = f;
  const unsigned r = c.u + 0x7fffu + ((c.u >> 16) & 1u);
  return (ushort)(r >> 16);
}
__device__ __forceinline__ float bf2f(ushort h) {
  union { unsigned u; float f; } c; c.u = ((unsigned)h) << 16;
  return c.f;
}

#define GLOAD16(g, l)                                                        \
  __builtin_amdgcn_global_load_lds(                                          \
      (const __attribute__((address_space(1))) void*)(g),                    \
      (__attribute__((address_space(3))) void*)(l), 16, 0, 0)

// ---------------- sinv[c] = 1/softplus(sp[c]) ----------------
__global__ void scale_kernel(const float* __restrict__ sp, float* __restrict__ sinv)
{
  const int c = threadIdx.x;
  sinv[c] = 1.f / softplusf(sp[c]);
}

// ---------------- fp32 -> bf16 (hi only, RNE) ----------------
__global__ __launch_bounds__(256) void cvt_hi(const float* __restrict__ in,
                                              ushort* __restrict__ hi)
{
  const size_t i = (size_t)blockIdx.x * 256 + threadIdx.x;
  const float4 a = ((const float4*)in)[i * 2];
  const float4 b = ((const float4*)in)[i * 2 + 1];
  const float f[8] = {a.x, a.y, a.z, a.w, b.x, b.y, b.z, b.w};
  u16x8 h;
  #pragma unroll
  for (int j = 0; j < 8; ++j) h[j] = f2bf(f[j]);
  *(u16x8*)&hi[i * 8] = h;
}

// ---------------- fp32 KxN weight -> bf16 hi/lo, transposed to NxK ----------------
__global__ __launch_bounds__(256) void cvt_w_t(const float* __restrict__ in,
                                               ushort* __restrict__ hi,
                                               ushort* __restrict__ lo, int Nn)
{
  const int t  = blockIdx.x * 256 + threadIdx.x;
  const int n  = t >> 6;
  const int k8 = (t & 63) * 8;
  u16x8 h, l;
  #pragma unroll
  for (int j = 0; j < 8; ++j) {
    const float v = in[(size_t)(k8 + j) * Nn + n];
    const ushort hb = f2bf(v);
    h[j] = hb;
    l[j] = f2bf(v - bf2f(hb));
  }
  *(u16x8*)&hi[(size_t)n * 512 + k8] = h;
  *(u16x8*)&lo[(size_t)n * 512 + k8] = l;
}

// ---------------- 2-pass split-bf16 MFMA GEMM: out = act(Ah @ (Bh+Bl)^T (+bias)) ----------------
// A: M x 512 bf16 (hi only). B: ncolb*128 x 512 K-contig hi+lo (weights exact to ~2^-17).
// 128x128 tile, BK=32, 4 waves, double-buffered (2x24KB LDS -> 3 blocks/CU).
__global__ __launch_bounds__(256, 3) void gemm_mfma2(
    const ushort* __restrict__ Ah,
    const ushort* __restrict__ Bh, const ushort* __restrict__ Bl,
    const float* __restrict__ bias,
    float* __restrict__ out0, float* __restrict__ out1, float* __restrict__ out2,
    int ncolb, int s1, int s2, int r0, int r1, int r2)
{
  __shared__ ushort lds[2][12288];  // per buf: AH[4096] BH[4096] BL[4096]
  const int tid = threadIdx.x;
  const int bid = blockIdx.x;
  const int loc = bid >> 3;
  const int xcd = bid & 7;
  const int row0 = ((xcd << 5) + loc / ncolb) * 128;
  const int col0 = (loc % ncolb) * 128;

  const int lane = tid & 63;
  const int li   = lane & 15;
  const int kq   = lane >> 4;
  const int wr   = ((tid >> 7) & 1) * 64;
  const int wc   = ((tid >> 6) & 1) * 64;
  const int w64  = tid & 192;

  f32x4 acc[4][4] = {};

  auto STAGE = [&](int buf, int k0) {
    ushort* l = &lds[buf][0];
    #pragma unroll
    for (int half = 0; half < 2; ++half) {
      const int c   = half * 256 + tid;       // chunk 0..511
      const int cw  = half * 256 + w64;       // wave-uniform base
      const int kb  = c >> 7;                 // 0..3
      const int idx = c & 127;                // row (A) / col (B)
      const size_t gA = (size_t)(row0 + idx) * 512 + k0 + kb * 8;
      const size_t gB = (size_t)(col0 + idx) * 512 + k0 + kb * 8;
      GLOAD16(Ah + gA, &l[       cw * 8]);
      GLOAD16(Bh + gB, &l[4096 + cw * 8]);
      GLOAD16(Bl + gB, &l[8192 + cw * 8]);
    }
  };

  auto COMPUTE = [&](int buf) {
    const ushort* l = &lds[buf][0];
    bf16x8 bhv[4], blv[4];
    #pragma unroll
    for (int n = 0; n < 4; ++n) {
      const int off = (kq * 128 + wc + n * 16 + li) * 8;
      bhv[n] = *(const bf16x8*)&l[4096 + off];
      blv[n] = *(const bf16x8*)&l[8192 + off];
    }
    __builtin_amdgcn_s_setprio(1);
    #pragma unroll
    for (int m = 0; m < 4; ++m) {
      const int off = (kq * 128 + wr + m * 16 + li) * 8;
      const bf16x8 ahm = *(const bf16x8*)&l[off];
      #pragma unroll
      for (int n = 0; n < 4; ++n) {
        acc[m][n] = __builtin_amdgcn_mfma_f32_16x16x32_bf16(ahm, bhv[n], acc[m][n], 0, 0, 0);
        acc[m][n] = __builtin_amdgcn_mfma_f32_16x16x32_bf16(ahm, blv[n], acc[m][n], 0, 0, 0);
      }
    }
    __builtin_amdgcn_s_setprio(0);
  };

  STAGE(0, 0);
  __syncthreads();
  #pragma unroll 1
  for (int t = 0; t < 7; ++t) {
    STAGE(1, (2 * t + 1) * 32);
    COMPUTE(0);
    __syncthreads();
    STAGE(0, (2 * t + 2) * 32);
    COMPUTE(1);
    __syncthreads();
  }
  STAGE(1, 480);
  COMPUTE(0);
  __syncthreads();
  COMPUTE(1);

  // epilogue: C/D map col=lane&15, row=(lane>>4)*4+reg
  float* dest; int cbase, relu;
  if (col0 < s1)      { dest = out0; cbase = 0;  relu = r0; }
  else if (col0 < s2) { dest = out1; cbase = s1; relu = r1; }
  else                { dest = out2; cbase = s2; relu = r2; }
  #pragma unroll
  for (int m = 0; m < 4; ++m) {
    #pragma unroll
    for (int n = 0; n < 4; ++n) {
      const int col = col0 + wc + n * 16 + li;
      const int row = row0 + wr + m * 16 + kq * 4;
      const float bv = bias ? bias[col] : 0.f;
      #pragma unroll
      for (int r = 0; r < 4; ++r) {
        float v = acc[m][n][r] + bv;
        if (relu) v = fmaxf(v, 0.f) + 1e-6f;
        dest[(size_t)(row + r) * 512 + (col - cbase)] = v;
      }
    }
  }
}

// ---------------- focus on q and k in one launch ----------------
__global__ __launch_bounds__(256) void focus2(float* __restrict__ qb, float* __restrict__ kb,
                                              const float* __restrict__ sinv)
{
  const int rid  = blockIdx.x * 4 + (threadIdx.x >> 6);
  const int lane = threadIdx.x & 63;
  float* t = (rid < B_ * N_) ? qb : kb;
  const int row = rid & (B_ * N_ - 1);
  float* p = t + (size_t)row * C_ + lane * 8;
  const float4 a = *(const float4*)p;
  const float4 b = *(const float4*)(p + 4);
  const float4 sa = *(const float4*)&sinv[lane * 8];
  const float4 sb = *(const float4*)&sinv[lane * 8 + 4];
  float tv[8] = {a.x * sa.x, a.y * sa.y, a.z * sa.z, a.w * sa.w,
                 b.x * sb.x, b.y * sb.y, b.z * sb.z, b.w * sb.w};
  float s2 = 0.f, s6 = 0.f;
  #pragma unroll
  for (int i = 0; i < 8; ++i) {
    const float x = tv[i];
    const float x3 = x * x * x;
    s2 = fmaf(x, x, s2);
    s6 = fmaf(x3, x3, s6);
  }
  #pragma unroll
  for (int off = 32; off > 0; off >>= 1) {
    s2 += __shfl_xor(s2, off);
    s6 += __shfl_xor(s6, off);
  }
  const float f = sqrtf(s2 / s6);
  float o[8];
  #pragma unroll
  for (int i = 0; i < 8; ++i) o[i] = tv[i] * tv[i] * tv[i] * f;
  *(float4*)p       = make_float4(o[0], o[1], o[2], o[3]);
  *(float4*)(p + 4) = make_float4(o[4], o[5], o[6], o[7]);
}

// ---------------- kvm[bh][c][d] = sum_n k*v ; fused ksum ----------------
__global__ __launch_bounds__(256) void kvm_kernel(
    const float* __restrict__ kf, const float* __restrict__ vf,
    float* __restrict__ kvm, float* __restrict__ ksum)
{
  __shared__ float Ks[32][68];
  __shared__ float Vs[32][68];
  const int bh = blockIdx.x, bb = bh >> 3, h = bh & 7;
  const int n0 = blockIdx.y * 256;
  const int tid = threadIdx.x;
  const int tx = tid & 15, ty = tid >> 4;
  const int r  = tid >> 3;
  const int cg = (tid & 7) * 8;
  float acc[4][4] = {};
  float ks[8] = {};
  for (int nb = 0; nb < 256; nb += 32) {
    const size_t base = ((size_t)(bb * N_ + n0 + nb + r)) * C_ + h * 64 + cg;
    const float4 k0v = *(const float4*)&kf[base];
    const float4 k1v = *(const float4*)&kf[base + 4];
    *(float4*)&Ks[r][cg]     = k0v;
    *(float4*)&Ks[r][cg + 4] = k1v;
    ks[0] += k0v.x; ks[1] += k0v.y; ks[2] += k0v.z; ks[3] += k0v.w;
    ks[4] += k1v.x; ks[5] += k1v.y; ks[6] += k1v.z; ks[7] += k1v.w;
    *(float4*)&Vs[r][cg]     = *(const float4*)&vf[base];
    *(float4*)&Vs[r][cg + 4] = *(const float4*)&vf[base + 4];
    __syncthreads();
    #pragma unroll
    for (int kk = 0; kk < 32; ++kk) {
      const float4 a = *(const float4*)&Ks[kk][ty * 4];
      const float4 c = *(const float4*)&Vs[kk][tx * 4];
      const float av[4] = {a.x, a.y, a.z, a.w};
      const float bv[4] = {c.x, c.y, c.z, c.w};
      #pragma unroll
      for (int i = 0; i < 4; ++i)
        #pragma unroll
        for (int j = 0; j < 4; ++j)
          acc[i][j] = fmaf(av[i], bv[j], acc[i][j]);
    }
    __syncthreads();
  }
  #pragma unroll
  for (int i = 0; i < 4; ++i)
    #pragma unroll
    for (int j = 0; j < 4; ++j)
      atomicAdd(&kvm[(bh * 64 + ty * 4 + i) * 64 + tx * 4 + j], acc[i][j]);
  #pragma unroll
  for (int j = 0; j < 8; ++j) {
    float s = ks[j];
    s += __shfl_xor(s, 8);
    s += __shfl_xor(s, 16);
    s += __shfl_xor(s, 32);
    if ((tid & 56) == 0) atomicAdd(&ksum[bh * 64 + cg + j], s);
  }
}

// ---------------- out = z * (q @ kvm), z fused ----------------
__global__ __launch_bounds__(256) void attnout_kernel(
    const float* __restrict__ qf, const float* __restrict__ kvm,
    const float* __restrict__ ksum, float* __restrict__ out)
{
  __shared__ float Qs[64][68];
  __shared__ float Ms[64][68];
  __shared__ float zrow[64];
  const int bh = blockIdx.x, bb = bh >> 3, h = bh & 7;
  const int n0 = blockIdx.y * 64;
  const int tid = threadIdx.x;
  {
    const int r  = tid >> 2;
    const int cg = (tid & 3) * 16;
    #pragma unroll
    for (int u = 0; u < 16; u += 4) {
      const float4 v = *(const float4*)&qf[((size_t)(bb * N_ + n0 + r)) * C_ + h * 64 + cg + u];
      Qs[cg + u + 0][r] = v.x;
      Qs[cg + u + 1][r] = v.y;
      Qs[cg + u + 2][r] = v.z;
      Qs[cg + u + 3][r] = v.w;
      *(float4*)&Ms[r][cg + u] = *(const float4*)&kvm[(bh * 64 + r) * 64 + cg + u];
    }
  }
  __syncthreads();
  {
    const int r  = tid >> 2;
    const int cq = (tid & 3) * 16;
    float p = 0.f;
    #pragma unroll
    for (int u = 0; u < 16; ++u) p = fmaf(Qs[cq + u][r], ksum[bh * 64 + cq + u], p);
    p += __shfl_xor(p, 1);
    p += __shfl_xor(p, 2);
    if ((tid & 3) == 0) zrow[r] = 1.f / (p + 1e-6f);
  }
  const int tx = tid & 15, ty = tid >> 4;
  float acc[4][4] = {};
  #pragma unroll
  for (int c = 0; c < 64; ++c) {
    const float4 a = *(const float4*)&Qs[c][ty * 4];
    const float4 b = *(const float4*)&Ms[c][tx * 4];
    const float av[4] = {a.x, a.y, a.z, a.w};
    const float bv[4] = {b.x, b.y, b.z, b.w};
    #pragma unroll
    for (int i = 0; i < 4; ++i)
      #pragma unroll
      for (int j = 0; j < 4; ++j)
        acc[i][j] = fmaf(av[i], bv[j], acc[i][j]);
  }
  __syncthreads();
  #pragma unroll
  for (int i = 0; i < 4; ++i) {
    const int n = n0 + ty * 4 + i;
    const float zv = zrow[ty * 4 + i];
    *(float4*)&out[((size_t)(bb * N_ + n)) * C_ + h * 64 + tx * 4] =
        make_float4(acc[i][0] * zv, acc[i][1] * zv, acc[i][2] * zv, acc[i][3] * zv);
  }
}

// ---------------- depthwise 5x5 conv, register-rolling; emits bf16 (hi only) proj input ----------------
__global__ __launch_bounds__(256) void dwconv_hi(
    const float* __restrict__ qf, const float* __restrict__ w,
    const float* __restrict__ wb, const float* __restrict__ ano,
    ushort* __restrict__ oh)
{
  __shared__ float ws_[64 * 25];
  const int tid = threadIdx.x;
  for (int i = tid; i < 64 * 25; i += 256) ws_[i] = w[i];
  __syncthreads();

  const int bh = blockIdx.x, bb = bh >> 3, h = bh & 7;
  const int hd = tid & 63;
  const int s  = blockIdx.y * 4 + (tid >> 6);
  const int x  = s & 63;
  const int y0 = (s >> 6) * 8;

  float wreg[25];
  #pragma unroll
  for (int i = 0; i < 25; ++i) wreg[i] = ws_[hd * 25 + i];

  float acc[8];
  const float bias = wb[hd];
  #pragma unroll
  for (int j = 0; j < 8; ++j) acc[j] = bias;

  const float* base = qf + (size_t)bb * N_ * C_ + h * 64 + hd;
  #pragma unroll
  for (int kx = 0; kx < 5; ++kx) {
    const int xx  = x + kx - 2;
    const bool xok = (unsigned)xx < 64u;
    const int xxc = min(max(xx, 0), 63);
    float col[12];
    #pragma unroll
    for (int r = 0; r < 12; ++r) {
      const int yy  = y0 + r - 2;
      const bool ok = xok && ((unsigned)yy < 64u);
      const int yyc = min(max(yy, 0), 63);
      const float v = base[(size_t)(yyc * 64 + xxc) * C_];
      col[r] = ok ? v : 0.f;
    }
    #pragma unroll
    for (int ky = 0; ky < 5; ++ky) {
      const float wv = wreg[ky * 5 + kx];
      #pragma unroll
      for (int j = 0; j < 8; ++j)
        acc[j] = fmaf(wv, col[j + ky], acc[j]);
    }
  }

  #pragma unroll
  for (int j = 0; j < 8; ++j) {
    const int p = (y0 + j) * 64 + x;
    const size_t idx = ((size_t)(bb * N_ + p)) * C_ + h * 64 + hd;
    oh[idx] = f2bf(ano[idx] + acc[j]);
  }
}

extern "C" void kernel_launch(void* const* d_in, const int* in_sizes, int n_in,
                              void* d_out, int out_size, void* d_ws, size_t ws_size,
                              hipStream_t stream) {
  (void)in_sizes; (void)n_in; (void)out_size; (void)ws_size;
  const float* x     = (const float*)d_in[0];
  const float* Wq    = (const float*)d_in[1];
  const float* Wkv   = (const float*)d_in[2];
  const float* Wp    = (const float*)d_in[3];
  const float* bp    = (const float*)d_in[4];
  const float* sp    = (const float*)d_in[5];
  const float* dwc_w = (const float*)d_in[6];
  const float* dwc_b = (const float*)d_in[7];
  float* out = (float*)d_out;

  char* ws = (char*)d_ws;
  ushort* xh   = (ushort*)ws;                        // 32MB: x hi; later proj-input hi
  float*  qbuf = (float*)(ws + 67108864ull);         // 64MB focused q
  float*  kbuf = (float*)(ws + 134217728ull);        // 64MB k; later ano
  char*   w0   = ws + 201326592ull;
  ushort* Bh  = (ushort*)w0;                         // 1536x512 fused [Wq|Wkv]^T hi
  ushort* Bl  = Bh + 786432;                         // lo
  ushort* Wph = Bl + 786432;                         // 512x512
  ushort* Wpl = Wph + 262144;
  float*  kvmb = (float*)(Wpl + 262144);             // 1MB
  float*  ksum = kvmb + 262144;                      // 16KB
  float*  sinv = ksum + 4096;                        // 2KB
  float*  vbuf = out;                                // v aliases d_out
  float*  ano  = kbuf;                               // attn-out aliases k

  const int M = B_ * N_;  // 32768

  scale_kernel<<<1, 512, 0, stream>>>(sp, sinv);
  cvt_hi<<<8192, 256, 0, stream>>>(x, xh);
  cvt_w_t<<<128, 256, 0, stream>>>(Wq, Bh, Bl, 512);
  cvt_w_t<<<256, 256, 0, stream>>>(Wkv, Bh + 262144, Bl + 262144, 1024);
  cvt_w_t<<<128, 256, 0, stream>>>(Wp, Wph, Wpl, 512);
  // fused q|k|v GEMM: cols [0,512)->q relu, [512,1024)->k relu, [1024,1536)->v
  gemm_mfma2<<<256 * 12, 256, 0, stream>>>(
      xh, Bh, Bl, nullptr, qbuf, kbuf, vbuf, 12, 512, 1024, 1, 1, 0);
  focus2<<<2 * M / 4, 256, 0, stream>>>(qbuf, kbuf, sinv);
  hipMemsetAsync(kvmb, 0, (262144 + 4096) * sizeof(float), stream);
  kvm_kernel<<<dim3(BH_, 16), 256, 0, stream>>>(kbuf, vbuf, kvmb, ksum);
  attnout_kernel<<<dim3(BH_, N_ / 64), 256, 0, stream>>>(qbuf, kvmb, ksum, ano);
  dwconv_hi<<<dim3(BH_, 128), 256, 0, stream>>>(qbuf, dwc_w, dwc_b, ano, xh);
  // proj
  gemm_mfma2<<<256 * 4, 256, 0, stream>>>(
      xh, Wph, Wpl, bp, out, out, out, 4, 512, 512, 0, 0, 0);
}